// Round 5
// baseline (366.188 us; speedup 1.0000x reference)
//
#include <hip/hip_runtime.h>

#define KC 512
#define NR 65536

// d_out layout (floats), reference return order:
// quantize_st[4194304], diff[1], embed_ind[65536], embed_new[32768],
// new_cluster_size[512], new_embed_avg[32768]
#define OFF_Q     0
#define OFF_DIFF  4194304
#define OFF_IND   4194305
#define OFF_ENEW  4259841
#define OFF_NCS   4292609
#define OFF_NAVG  4293121

// ws layout (floats)
#define WS_ET    0        // 32768: embed transposed [K][D]
#define WS_C     32768    // 512:   0.5*||e_k||^2
#define WS_CNT   33280    // 512:   one-hot counts
#define WS_ESUM  33792    // 32768: embed_sum transposed [K][D]
#define WS_DIFF  66560    // 1:     sum of squared diff
#define WS_NTOT  66561    // 1:     sum of new_cluster_size

// Prep: transpose embed [D][K] -> Et [K][D], code-norm bias, zero accumulators.
__global__ __launch_bounds__(256) void k_prep(const float* __restrict__ embed,
                                              float* __restrict__ ws) {
    int i = blockIdx.x * 256 + threadIdx.x;
    if (i < 512 + 32768 + 2) ws[WS_CNT + i] = 0.0f;   // counts, esum, diff, ntot
    if (i < 32768) {
        int k = i >> 6, d = i & 63;
        ws[WS_ET + i] = embed[d * KC + k];
    }
    if (i < 512) {
        float s = 0.0f;
        #pragma unroll
        for (int d = 0; d < 64; ++d) { float e = embed[d * KC + i]; s = fmaf(e, e, s); }
        ws[WS_C + i] = 0.5f * s;
    }
}

// Scalar-E + LDS-X GEMM. Block = 512 threads = 8 waves; block owns 64 rows.
// lane -> row (base+lane); wave -> 64-code chunk (wave-uniform k -> s_load E).
// X tile lives in LDS as XQ[dq][row] float4: XQ[dq][lane] is a contiguous,
// conflict-free ds_read_b128. Inner loop: 1 ds_read_b128 + 32 v_fma(v,s,v).
#define FMAROW(SS, RR) \
    SS = fmaf(xq.x, e[RR*64 + d0 + 0], SS); \
    SS = fmaf(xq.y, e[RR*64 + d0 + 1], SS); \
    SS = fmaf(xq.z, e[RR*64 + d0 + 2], SS); \
    SS = fmaf(xq.w, e[RR*64 + d0 + 3], SS);

__global__ __launch_bounds__(512, 8) void k_main(const float* __restrict__ input,
                                                 const float* __restrict__ Et,   // [512][64]
                                                 const float* __restrict__ c,
                                                 float* __restrict__ out,
                                                 float* __restrict__ counts,
                                                 float* __restrict__ esum,
                                                 float* __restrict__ diffsum) {
    __shared__ float4 XQ[16][64];     // 16 KB: XQ[dq][row] = x[row][4dq..4dq+3]
    __shared__ float  sbest[8][64];
    __shared__ int    sidx[8][64];
    __shared__ int    fbk[64];
    __shared__ float  sred[1];        // sum of x^2 over the block

    const int t     = threadIdx.x;
    const int lane  = t & 63;
    const int chunk = __builtin_amdgcn_readfirstlane(t >> 6);  // 0..7, uniform
    const int base  = blockIdx.x * 64;

    if (t == 0) sred[0] = 0.0f;

    // Stage X tile (coalesced): thread t -> row t>>3, float4 pair t&7.
    float xs;
    {
        int r = t >> 3, q8 = t & 7;
        const float4* xp = reinterpret_cast<const float4*>(input) + (size_t)(base + r) * 16 + q8 * 2;
        float4 a = xp[0], b = xp[1];
        xs = a.x*a.x + a.y*a.y + a.z*a.z + a.w*a.w
           + b.x*b.x + b.y*b.y + b.z*b.z + b.w*b.w;
        XQ[q8 * 2 + 0][r] = a;
        XQ[q8 * 2 + 1][r] = b;
        #pragma unroll
        for (int off = 32; off > 0; off >>= 1) xs += __shfl_down(xs, off);
    }
    __syncthreads();
    if (lane == 0) atomicAdd(&sred[0], xs);   // 8 adds (one per wave)

    // Main loop: wave's 64 codes, 8 at a time (8 independent chains).
    const int k0 = chunk * 64;
    float best = -3.0e38f; int bk = k0;
    #pragma unroll 2
    for (int kk = 0; kk < 64; kk += 8) {
        const int k = k0 + kk;
        const float* __restrict__ e = Et + (size_t)k * 64;   // wave-uniform -> s_load
        float s0 = -c[k+0], s1 = -c[k+1], s2 = -c[k+2], s3 = -c[k+3];
        float s4 = -c[k+4], s5 = -c[k+5], s6 = -c[k+6], s7 = -c[k+7];
        #pragma unroll
        for (int dq = 0; dq < 16; ++dq) {
            float4 xq = XQ[dq][lane];            // ds_read_b128, conflict-free
            const int d0 = dq * 4;
            FMAROW(s0, 0) FMAROW(s1, 1) FMAROW(s2, 2) FMAROW(s3, 3)
            FMAROW(s4, 4) FMAROW(s5, 5) FMAROW(s6, 6) FMAROW(s7, 7)
        }
        if (s0 > best) { best = s0; bk = k + 0; }
        if (s1 > best) { best = s1; bk = k + 1; }
        if (s2 > best) { best = s2; bk = k + 2; }
        if (s3 > best) { best = s3; bk = k + 3; }
        if (s4 > best) { best = s4; bk = k + 4; }
        if (s5 > best) { best = s5; bk = k + 5; }
        if (s6 > best) { best = s6; bk = k + 6; }
        if (s7 > best) { best = s7; bk = k + 7; }
    }
    sbest[chunk][lane] = best;
    sidx[chunk][lane]  = bk;
    __syncthreads();

    // Combine 8 chunks (ascending chunk = ascending k; strict > = lowest-k tie).
    if (chunk == 0) {
        float b = sbest[0][lane]; int k = sidx[0][lane];
        #pragma unroll
        for (int cc = 1; cc < 8; ++cc) {
            float v = sbest[cc][lane]; int kk2 = sidx[cc][lane];
            if (v > b) { b = v; k = kk2; }
        }
        fbk[lane] = k;
        out[OFF_IND + base + lane] = (float)k;
        atomicAdd(&counts[k], 1.0f);
        // diff partial: sum_rows (||x||^2) - 2 * sum_rows best
        float bs = b;
        #pragma unroll
        for (int off = 32; off > 0; off >>= 1) bs += __shfl_down(bs, off);
        if (lane == 0) atomicAdd(diffsum, sred[0] - 2.0f * bs);
    }
    __syncthreads();

    // Epilogue: quantize gather + coalesced EMA scatter. lane = d; wave -> 8 rows.
    #pragma unroll
    for (int j = 0; j < 8; ++j) {
        int r = chunk * 8 + j;
        int k = fbk[r];
        float e = Et[(size_t)k * 64 + lane];
        out[OFF_Q + (size_t)(base + r) * 64 + lane] = e;
        atomicAdd(&esum[k * 64 + lane], input[(size_t)(base + r) * 64 + lane]);
    }
}

// new_cluster_size + its sum + diff finalize (single block).
__global__ __launch_bounds__(512) void k_ncs(const float* __restrict__ cluster_size,
                                             const float* __restrict__ ws,
                                             float* __restrict__ out,
                                             float* __restrict__ wsw) {
    __shared__ float red[512];
    int t = threadIdx.x;
    float ncs = cluster_size[t] * 0.99f + (1.0f - 0.99f) * ws[WS_CNT + t];
    out[OFF_NCS + t] = ncs;
    red[t] = ncs;
    __syncthreads();
    for (int off = 256; off > 0; off >>= 1) {
        if (t < off) red[t] += red[t + off];
        __syncthreads();
    }
    if (t == 0) {
        wsw[WS_NTOT] = red[0];
        out[OFF_DIFF] = ws[WS_DIFF] * (1.0f / 4194304.0f);
    }
}

// new_embed_avg + embed_new.
__global__ __launch_bounds__(512) void k_emb(const float* __restrict__ embed_avg,
                                             const float* __restrict__ ws,
                                             float* __restrict__ out) {
    int d = blockIdx.x;
    int t = threadIdx.x;
    float ncs = out[OFF_NCS + t];
    float ntot = ws[WS_NTOT];
    float csk = (ncs + 1e-5f) / (ntot + 512.0f * 1e-5f) * ntot;
    int idx = d * KC + t;
    float avg = embed_avg[idx] * 0.99f + (1.0f - 0.99f) * ws[WS_ESUM + t * 64 + d];
    out[OFF_NAVG + idx] = avg;
    out[OFF_ENEW + idx] = avg / csk;
}

extern "C" void kernel_launch(void* const* d_in, const int* in_sizes, int n_in,
                              void* d_out, int out_size, void* d_ws, size_t ws_size,
                              hipStream_t stream) {
    const float* input        = (const float*)d_in[0];
    const float* embed        = (const float*)d_in[1];
    const float* cluster_size = (const float*)d_in[2];
    const float* embed_avg    = (const float*)d_in[3];
    float* out = (float*)d_out;
    float* ws  = (float*)d_ws;

    k_prep<<<131, 256, 0, stream>>>(embed, ws);
    k_main<<<1024, 512, 0, stream>>>(input, ws + WS_ET, ws + WS_C, out,
                                     ws + WS_CNT, ws + WS_ESUM, ws + WS_DIFF);
    k_ncs<<<1, 512, 0, stream>>>(cluster_size, ws, out, ws);
    k_emb<<<64, 512, 0, stream>>>(embed_avg, ws, out);
}

// Round 6
// 142.514 us; speedup vs baseline: 2.5695x; 2.5695x over previous
//
#include <hip/hip_runtime.h>

#define KC 512
#define NR 65536

// d_out layout (floats), reference return order:
// quantize_st[4194304], diff[1], embed_ind[65536], embed_new[32768],
// new_cluster_size[512], new_embed_avg[32768]
#define OFF_Q     0
#define OFF_DIFF  4194304
#define OFF_IND   4194305
#define OFF_ENEW  4259841
#define OFF_NCS   4292609
#define OFF_NAVG  4293121

// ws layout (floats)
#define WS_ET    0        // 32768: embed transposed [K][D]
#define WS_C     32768    // 512:   0.5*||e_k||^2
#define WS_CNT   33280    // 512:   one-hot counts
#define WS_ESUM  33792    // 32768: embed_sum transposed [K][D]
#define WS_DIFF  66560    // 1:     sum of squared diff
#define WS_NTOT  66561    // 1:     sum of new_cluster_size

// Prep: transpose embed [D][K] -> Et [K][D], code-norm bias, zero accumulators.
__global__ __launch_bounds__(256) void k_prep(const float* __restrict__ embed,
                                              float* __restrict__ ws) {
    int i = blockIdx.x * 256 + threadIdx.x;
    if (i < 512 + 32768 + 2) ws[WS_CNT + i] = 0.0f;   // counts, esum, diff, ntot
    if (i < 32768) {
        int k = i >> 6, d = i & 63;
        ws[WS_ET + i] = embed[d * KC + k];
    }
    if (i < 512) {
        float s = 0.0f;
        #pragma unroll
        for (int d = 0; d < 64; ++d) { float e = embed[d * KC + i]; s = fmaf(e, e, s); }
        ws[WS_C + i] = 0.5f * s;
    }
}

// Scalar-E + LDS-X GEMM. Block = 512 threads = 8 waves; block owns 64 rows.
// lane -> row (base+lane); wave -> 64-code chunk (wave-uniform k -> s_load E).
// X tile lives in LDS as XQ[dq][row] float4: XQ[dq][lane] is a contiguous,
// conflict-free ds_read_b128. Inner loop: 1 ds_read_b128 + 32 v_fma(v,s,v).
// launch_bounds(512,4): VGPR cap 128 -> NO spills (round 5's (512,8)=64-cap
// spilled the 8 accumulator chains to scratch -> 712 MB of HBM spill traffic).
#define FMAROW(SS, RR) \
    SS = fmaf(xq.x, e[RR*64 + d0 + 0], SS); \
    SS = fmaf(xq.y, e[RR*64 + d0 + 1], SS); \
    SS = fmaf(xq.z, e[RR*64 + d0 + 2], SS); \
    SS = fmaf(xq.w, e[RR*64 + d0 + 3], SS);

__global__ __launch_bounds__(512, 4) void k_main(const float* __restrict__ input,
                                                 const float* __restrict__ Et,   // [512][64]
                                                 const float* __restrict__ c,
                                                 float* __restrict__ out,
                                                 float* __restrict__ counts,
                                                 float* __restrict__ esum,
                                                 float* __restrict__ diffsum) {
    __shared__ float4 XQ[16][64];     // 16 KB: XQ[dq][row] = x[row][4dq..4dq+3]
    __shared__ float  sbest[8][64];
    __shared__ int    sidx[8][64];
    __shared__ int    fbk[64];
    __shared__ float  sred[1];        // sum of x^2 over the block

    const int t     = threadIdx.x;
    const int lane  = t & 63;
    const int chunk = __builtin_amdgcn_readfirstlane(t >> 6);  // 0..7, uniform
    const int base  = blockIdx.x * 64;

    if (t == 0) sred[0] = 0.0f;

    // Stage X tile (coalesced): thread t -> row t>>3, float4 pair t&7.
    float xs;
    {
        int r = t >> 3, q8 = t & 7;
        const float4* xp = reinterpret_cast<const float4*>(input) + (size_t)(base + r) * 16 + q8 * 2;
        float4 a = xp[0], b = xp[1];
        xs = a.x*a.x + a.y*a.y + a.z*a.z + a.w*a.w
           + b.x*b.x + b.y*b.y + b.z*b.z + b.w*b.w;
        XQ[q8 * 2 + 0][r] = a;
        XQ[q8 * 2 + 1][r] = b;
        #pragma unroll
        for (int off = 32; off > 0; off >>= 1) xs += __shfl_down(xs, off);
    }
    __syncthreads();
    if (lane == 0) atomicAdd(&sred[0], xs);   // 8 adds (one per wave)

    // Main loop: wave's 64 codes, 8 at a time (8 independent chains).
    const int k0 = chunk * 64;
    float best = -3.0e38f; int bk = k0;
    for (int kk = 0; kk < 64; kk += 8) {
        const int k = k0 + kk;
        const float* __restrict__ e = Et + (size_t)k * 64;   // wave-uniform -> s_load
        float s0 = -c[k+0], s1 = -c[k+1], s2 = -c[k+2], s3 = -c[k+3];
        float s4 = -c[k+4], s5 = -c[k+5], s6 = -c[k+6], s7 = -c[k+7];
        #pragma unroll
        for (int dq = 0; dq < 16; ++dq) {
            float4 xq = XQ[dq][lane];            // ds_read_b128, conflict-free
            const int d0 = dq * 4;
            FMAROW(s0, 0) FMAROW(s1, 1) FMAROW(s2, 2) FMAROW(s3, 3)
            FMAROW(s4, 4) FMAROW(s5, 5) FMAROW(s6, 6) FMAROW(s7, 7)
        }
        if (s0 > best) { best = s0; bk = k + 0; }
        if (s1 > best) { best = s1; bk = k + 1; }
        if (s2 > best) { best = s2; bk = k + 2; }
        if (s3 > best) { best = s3; bk = k + 3; }
        if (s4 > best) { best = s4; bk = k + 4; }
        if (s5 > best) { best = s5; bk = k + 5; }
        if (s6 > best) { best = s6; bk = k + 6; }
        if (s7 > best) { best = s7; bk = k + 7; }
    }
    sbest[chunk][lane] = best;
    sidx[chunk][lane]  = bk;
    __syncthreads();

    // Combine 8 chunks (ascending chunk = ascending k; strict > = lowest-k tie).
    if (chunk == 0) {
        float b = sbest[0][lane]; int k = sidx[0][lane];
        #pragma unroll
        for (int cc = 1; cc < 8; ++cc) {
            float v = sbest[cc][lane]; int kk2 = sidx[cc][lane];
            if (v > b) { b = v; k = kk2; }
        }
        fbk[lane] = k;
        out[OFF_IND + base + lane] = (float)k;
        atomicAdd(&counts[k], 1.0f);
        // diff partial: sum_rows (||x||^2) - 2 * sum_rows best
        float bs = b;
        #pragma unroll
        for (int off = 32; off > 0; off >>= 1) bs += __shfl_down(bs, off);
        if (lane == 0) atomicAdd(diffsum, sred[0] - 2.0f * bs);
    }
    __syncthreads();

    // Epilogue: quantize gather + coalesced EMA scatter. lane = d; wave -> 8 rows.
    #pragma unroll
    for (int j = 0; j < 8; ++j) {
        int r = chunk * 8 + j;
        int k = fbk[r];
        float e = Et[(size_t)k * 64 + lane];
        out[OFF_Q + (size_t)(base + r) * 64 + lane] = e;
        atomicAdd(&esum[k * 64 + lane], input[(size_t)(base + r) * 64 + lane]);
    }
}

// new_cluster_size + its sum + diff finalize (single block).
__global__ __launch_bounds__(512) void k_ncs(const float* __restrict__ cluster_size,
                                             const float* __restrict__ ws,
                                             float* __restrict__ out,
                                             float* __restrict__ wsw) {
    __shared__ float red[512];
    int t = threadIdx.x;
    float ncs = cluster_size[t] * 0.99f + (1.0f - 0.99f) * ws[WS_CNT + t];
    out[OFF_NCS + t] = ncs;
    red[t] = ncs;
    __syncthreads();
    for (int off = 256; off > 0; off >>= 1) {
        if (t < off) red[t] += red[t + off];
        __syncthreads();
    }
    if (t == 0) {
        wsw[WS_NTOT] = red[0];
        out[OFF_DIFF] = ws[WS_DIFF] * (1.0f / 4194304.0f);
    }
}

// new_embed_avg + embed_new.
__global__ __launch_bounds__(512) void k_emb(const float* __restrict__ embed_avg,
                                             const float* __restrict__ ws,
                                             float* __restrict__ out) {
    int d = blockIdx.x;
    int t = threadIdx.x;
    float ncs = out[OFF_NCS + t];
    float ntot = ws[WS_NTOT];
    float csk = (ncs + 1e-5f) / (ntot + 512.0f * 1e-5f) * ntot;
    int idx = d * KC + t;
    float avg = embed_avg[idx] * 0.99f + (1.0f - 0.99f) * ws[WS_ESUM + t * 64 + d];
    out[OFF_NAVG + idx] = avg;
    out[OFF_ENEW + idx] = avg / csk;
}

extern "C" void kernel_launch(void* const* d_in, const int* in_sizes, int n_in,
                              void* d_out, int out_size, void* d_ws, size_t ws_size,
                              hipStream_t stream) {
    const float* input        = (const float*)d_in[0];
    const float* embed        = (const float*)d_in[1];
    const float* cluster_size = (const float*)d_in[2];
    const float* embed_avg    = (const float*)d_in[3];
    float* out = (float*)d_out;
    float* ws  = (float*)d_ws;

    k_prep<<<131, 256, 0, stream>>>(embed, ws);
    k_main<<<1024, 512, 0, stream>>>(input, ws + WS_ET, ws + WS_C, out,
                                     ws + WS_CNT, ws + WS_ESUM, ws + WS_DIFF);
    k_ncs<<<1, 512, 0, stream>>>(cluster_size, ws, out, ws);
    k_emb<<<64, 512, 0, stream>>>(embed_avg, ws, out);
}